// Round 20
// baseline (302.133 us; speedup 1.0000x reference)
//
#include <hip/hip_runtime.h>

#define NB 65536
#define NTOT 704
#define NCLS 1000
#define NPAD 1024
#define KDIM 704

typedef __attribute__((ext_vector_type(8))) short bf16x8;
typedef __attribute__((ext_vector_type(4))) float f32x4;
typedef __attribute__((ext_vector_type(2))) float f32x2;

#define WB_ELEMS (NPAD * KDIM)

__device__ __forceinline__ f32x2 sp(float x) { return (f32x2){x, x}; }

template <int CTRL, int RMASK>
__device__ __forceinline__ float dpp_add(float v) {
  return v + __int_as_float(__builtin_amdgcn_update_dpp(0, __float_as_int(v), CTRL, RMASK, 0xF, true));
}
// full-wave sum -> uniform SGPR value (row reduce via DPP, cross-row via
// row_bcast15/31, readlane 63). No LGKM ops in the chain.
__device__ __forceinline__ float wsum_u(float v) {
  v = dpp_add<0xB1, 0xF>(v);    // quad_perm [1,0,3,2]
  v = dpp_add<0x4E, 0xF>(v);    // quad_perm [2,3,0,1]
  v = dpp_add<0x141, 0xF>(v);   // row_half_mirror
  v = dpp_add<0x140, 0xF>(v);   // row_mirror -> 16-lane row sums
  v = dpp_add<0x142, 0xA>(v);   // row_bcast15 -> rows 1,3
  v = dpp_add<0x143, 0xC>(v);   // row_bcast31 -> rows 2,3; lane63 = total
  return __int_as_float(__builtin_amdgcn_readlane(__float_as_int(v), 63));
}

template <int CTRL>
__device__ __forceinline__ float dpp_shuf(float v) {
  return __int_as_float(__builtin_amdgcn_update_dpp(0, __float_as_int(v), CTRL, 0xF, 0xF, true));
}
__device__ __forceinline__ float swz16(float v) {
  return __int_as_float(__builtin_amdgcn_ds_swizzle(__float_as_int(v), 0x401F)); // xor 16
}
__device__ __forceinline__ float wmax_f(float v) {
  v = fmaxf(v, dpp_shuf<0xB1>(v));
  v = fmaxf(v, dpp_shuf<0x4E>(v));
  v = fmaxf(v, dpp_shuf<0x141>(v));
  v = fmaxf(v, dpp_shuf<0x140>(v));
  v = fmaxf(v, swz16(v));
  v = fmaxf(v, __shfl_xor(v, 32, 64));
  return v;
}
__device__ __forceinline__ float wmin_f(float v) {
  v = fminf(v, dpp_shuf<0xB1>(v));
  v = fminf(v, dpp_shuf<0x4E>(v));
  v = fminf(v, dpp_shuf<0x141>(v));
  v = fminf(v, dpp_shuf<0x140>(v));
  v = fminf(v, swz16(v));
  v = fminf(v, __shfl_xor(v, 32, 64));
  return v;
}

__device__ __forceinline__ unsigned short f2bf(float v) {
  unsigned u = __float_as_uint(v);
  u = (u + 0x7FFFu + ((u >> 16) & 1u)) >> 16;   // RNE
  return (unsigned short)u;
}

__device__ __forceinline__ float freq_of(int i) {
  if (i < 64)       return 1.0f + 3.0f * (float)i * (1.0f / 63.0f);
  else if (i < 192) return 4.0f + 4.0f * (float)(i - 64) * (1.0f / 127.0f);
  else              return 30.0f + 50.0f * (float)(i - 192) * (1.0f / 511.0f);
}

// ---------------- oscillator sim + quantile gate -> rate(bf16) ----------------
// convw fused: first NPAD*KDIM/256 blocks also convert one W element to bf16.
__global__ __launch_bounds__(256) void sim_kernel(const float* __restrict__ x,
                                                  const float* __restrict__ p0,
                                                  const float* __restrict__ W,
                                                  unsigned short* __restrict__ Wb,
                                                  unsigned short* __restrict__ rateb) {
  // fused convw prologue (independent output; gemm launches after sim)
  {
    const int gid = blockIdx.x * 256 + threadIdx.x;
    if (gid < NPAD * KDIM) {
      const int n = gid / KDIM;
      Wb[gid] = f2bf((n < NCLS) ? W[gid] : 0.0f);
    }
  }

  const int wave = threadIdx.x >> 6;
  const int lane = threadIdx.x & 63;
  const int sample = blockIdx.x * 4 + wave;
  const size_t base = (size_t)sample * NTOT;

  // delta: scalar element (e=0); theta pair (1,2); gamma pairs (3,4)..(9,10)
  float sD, cD, ampD, dcD, dsD;
  f32x2 sPp[5], cPp[5], dc2[5], ds2[5], amp2[5];
  {
    const float p = p0[base + lane];
    sD = __builtin_amdgcn_sinf(p);
    cD = __builtin_amdgcn_cosf(p);
    ampD = fmaf(fabsf(x[base + lane]), 0.01f, 1.0f);
    const float rev = 0.01f * freq_of(lane);
    dcD = __builtin_amdgcn_cosf(rev);
    dsD = __builtin_amdgcn_sinf(rev);
  }
#pragma unroll
  for (int pr = 0; pr < 5; ++pr) {
    const int i0 = (1 + 2 * pr) * 64 + lane;
    const int i1 = i0 + 64;
    const float pa = p0[base + i0], pb = p0[base + i1];
    sPp[pr] = (f32x2){__builtin_amdgcn_sinf(pa), __builtin_amdgcn_sinf(pb)};
    cPp[pr] = (f32x2){__builtin_amdgcn_cosf(pa), __builtin_amdgcn_cosf(pb)};
    amp2[pr] = (f32x2){fmaf(fabsf(x[base + i0]), 0.01f, 1.0f),
                       fmaf(fabsf(x[base + i1]), 0.01f, 1.0f)};
    const float r0 = 0.01f * freq_of(i0);
    const float r1 = 0.01f * freq_of(i1);
    dc2[pr] = (f32x2){__builtin_amdgcn_cosf(r0), __builtin_amdgcn_cosf(r1)};
    ds2[pr] = (f32x2){__builtin_amdgcn_sinf(r0), __builtin_amdgcn_sinf(r1)};
  }

  float prodT = 1.0f, prodG = 1.0f;

#pragma unroll
  for (int st = 0; st < 5; ++st) {
    const float Sd = wsum_u(sD);
    const float Cd = wsum_u(cD);
    const float St = wsum_u(sPp[0].x + sPp[0].y);
    const float Ct = wsum_u(cPp[0].x + cPp[0].y);
    const f32x2 gs = (sPp[1] + sPp[2]) + (sPp[3] + sPp[4]);
    const f32x2 gc = (cPp[1] + cPp[2]) + (cPp[3] + cPp[4]);
    const float Sg = wsum_u(gs.x + gs.y);
    const float Cg = wsum_u(gc.x + gc.y);
    const float cpd = Cd * __builtin_amdgcn_rsqf(fmaf(Sd, Sd, Cd * Cd));
    const float cpt = Ct * __builtin_amdgcn_rsqf(fmaf(St, St, Ct * Ct));
    prodT *= fmaf(0.003f, cpd, 1.0f);
    prodG *= fmaf(0.003f, cpt, 1.0f);
    const float sdm = Sd * (0.02f / 64.0f),  cdm = Cd * (0.02f / 64.0f);
    const float stm = St * (0.02f / 128.0f), ctm = Ct * (0.02f / 128.0f);
    const float sgm = Sg * (0.02f / 512.0f), cgm = Cg * (0.02f / 512.0f);
    // delta (scalar), 1st-order rotor: cos(eps)~1, sin(eps)~eps (err eps^2/2 <= 2e-4)
    {
      const float eps = fmaf(-cdm, sD, sdm * cD);
      const float cd_ = fmaf(-dsD, eps, dcD);
      const float sd_ = fmaf(dcD, eps, dsD);
      const float sn = fmaf(cD, sd_, sD * cd_);
      const float cn = fmaf(-sD, sd_, cD * cd_);
      sD = sn; cD = cn;
    }
    // pairs (packed f32), 1st-order rotor
#pragma unroll
    for (int pr = 0; pr < 5; ++pr) {
      const f32x2 Sm = sp(pr == 0 ? stm : sgm);
      const f32x2 Cm = sp(pr == 0 ? ctm : cgm);
      const f32x2 s2 = sPp[pr], c2 = cPp[pr];
      const f32x2 eps = Sm * c2 - Cm * s2;
      const f32x2 cosd = dc2[pr] - ds2[pr] * eps;
      const f32x2 sind = ds2[pr] + dc2[pr] * eps;
      sPp[pr] = s2 * cosd + c2 * sind;
      cPp[pr] = c2 * cosd - s2 * sind;
    }
  }

  // rates + 14-bit keys
  float raw[11];
  unsigned kk[11];
  {
    const float h = 0.5f * ampD;
    raw[0] = fmaf(h, cD, h);
  }
  const float hT = 0.5f * prodT, hG = 0.5f * prodG;
#pragma unroll
  for (int pr = 0; pr < 5; ++pr) {
    const f32x2 h2 = amp2[pr] * sp(pr == 0 ? hT : hG);
    const f32x2 r2 = h2 * cPp[pr] + h2;
    raw[1 + 2 * pr] = r2.x;
    raw[2 + 2 * pr] = r2.y;
  }
#pragma unroll
  for (int e = 0; e < 11; ++e) kk[e] = (unsigned)(raw[e] * 8192.0f);

  // minimal B with count(k <= B) >= 633 — ballot+popcount (SALU-heavy)
  unsigned pre = 0;
#pragma unroll
  for (int bit = 13; bit >= 0; --bit) {
    const unsigned u = pre | ((1u << bit) - 1u);
    int cnt = 0;
#pragma unroll
    for (int e = 0; e < 11; ++e) cnt += (int)__popcll(__ballot(kk[e] <= u));
    if (cnt < 633) pre |= (1u << bit);
  }

  int clt = 0, ceq = 0;
#pragma unroll
  for (int e = 0; e < 11; ++e) {
    clt += (int)__popcll(__ballot(kk[e] < pre));
    ceq += (int)__popcll(__ballot(kk[e] == pre));
  }

  const float qv = 0.9f * 703.0f;
  float thr;
  if (clt + ceq >= 634) {
    // both order stats inside bucket (width 1/8192): center approx, err <= 1.2e-4
    thr = ((float)pre + 0.5f) * (1.0f / 8192.0f);
  } else {
    // exactly 633 values <= B: S632 = max(k==B), S633 = min(k>B)
    float mx = -1.0f, mn = 3.0e38f;
#pragma unroll
    for (int e = 0; e < 11; ++e) {
      mx = fmaxf(mx, (kk[e] == pre) ? raw[e] : -1.0f);
      mn = fminf(mn, (kk[e] > pre) ? raw[e] : 3.0e38f);
    }
    const float S632 = wmax_f(mx);
    const float S633 = wmin_f(mn);
    thr = S632 * (633.0f - qv) + S633 * (qv - 632.0f);
  }

#pragma unroll
  for (int e = 0; e < 11; ++e) {
    const float r = raw[e];
    const float t = __expf((thr - r) * 10.0f);
    const float sg = __builtin_amdgcn_rcpf(1.0f + t);
    rateb[base + e * 64 + lane] = f2bf(r * sg);
  }
}

// ---------------- bf16 MFMA GEMM: out = rate @ W^T + b ----------------
// R18 config (best measured: 150 us): BM=128, BN=256, BK=32, 8 waves
// (2Mx4N, wave tile 64x64), acc[4][4]=64 VGPR (fits (512,4) cap), LDS =
// 2dbuf x (8KB A + 16KB B) = 48 KB -> 2 blocks/CU. 2-phase counted pipeline
// (distance-2, stage-into-read-dbuf after lgkm-confirmed reads; vmcnt(3)
// gate). 64B-row swizzle slot = kq ^ ((row>>1)&3). No "memory" clobbers.
#define BK3 32
#define NK3 (KDIM / BK3)   // 22

#define FENCE __builtin_amdgcn_sched_barrier(0)
#define BAR   do { FENCE; __builtin_amdgcn_s_barrier(); FENCE; } while (0)
#define WVM3  do { asm volatile("s_waitcnt vmcnt(3)"); FENCE; } while (0)
#define WVM0  do { asm volatile("s_waitcnt vmcnt(0)"); FENCE; } while (0)
#define WLG0  do { asm volatile("s_waitcnt lgkmcnt(0)"); FENCE; } while (0)

__device__ __forceinline__ void gload16(const unsigned short* g, unsigned short* l) {
  __builtin_amdgcn_global_load_lds((const __attribute__((address_space(1))) void*)g,
                                   (__attribute__((address_space(3))) void*)l,
                                   16, 0, 0);
}

__global__ __launch_bounds__(512, 4) void gemm_kernel(const unsigned short* __restrict__ A,
                                                      const unsigned short* __restrict__ Bw,
                                                      const float* __restrict__ bias,
                                                      float* __restrict__ C) {
  // A: [dbuf][128 x 32] = 2 x 8 KB; B: [dbuf][256 x 32] = 2 x 16 KB -> 48 KB
  __shared__ __align__(16) unsigned short lsA[2 * 4096];
  __shared__ __align__(16) unsigned short lsB[2 * 8192];
  const int tid  = threadIdx.x;
  const int wave = tid >> 6;
  const int lane = tid & 63;

  // XCD-bijective swizzle: nwg = 2048 = 8 * 256
  const int bid = blockIdx.x;
  const int swz = (bid & 7) * 256 + (bid >> 3);
  const int bm = swz >> 2;     // 0..511
  const int bn = swz & 3;      // 0..3

  const int wr = wave >> 2;    // 0..1  (M half: 64 rows)
  const int wc = wave & 3;     // 0..3  (N quarter: 64 cols)

  f32x4 acc[4][4];
#pragma unroll
  for (int i = 0; i < 4; ++i)
#pragma unroll
    for (int j = 0; j < 4; ++j) acc[i][j] = (f32x4){0.f, 0.f, 0.f, 0.f};

  // staging: thread covers row tid>>2, 16B block tid&3; pre-swizzled source
  // col block = (tid&3) ^ ((row>>1)&3) where (row>>1)&3 = (tid>>3)&3.
  const int srow4 = tid >> 2;                        // 0..127
  const int ksrc  = ((tid & 3) ^ ((tid >> 3) & 3)) * 8;
  const unsigned short* Ab = A  + (size_t)(bm * 128) * KDIM;
  const unsigned short* Bb = Bw + (size_t)(bn * 256) * KDIM;

  // A: one load/thread (128 rows); B: two loads/thread (256 rows = 2 halves)
#define SA32(dst, k0)                                                                 \
  gload16(Ab + (size_t)(srow4) * KDIM + (k0) + ksrc, (dst) + tid * 8);
#define SB32(dst, k0)                                                                 \
  gload16(Bb + (size_t)(srow4) * KDIM + (k0) + ksrc, (dst) + tid * 8);                \
  gload16(Bb + (size_t)(128 + srow4) * KDIM + (k0) + ksrc, (dst) + 4096 + tid * 8);

  // prologue: tiles 0 -> dbuf0, 1 -> dbuf1 (6 loads/thread)
  SA32(lsA + 0 * 4096, 0)
  SB32(lsB + 0 * 8192, 0)
  SA32(lsA + 1 * 4096, BK3)
  SB32(lsB + 1 * 8192, BK3)

  const int l15 = lane & 15;
  const int kq  = lane >> 4;   // 0..3

  bf16x8 af[4];   // wave M tile (4 x 16 rows)
  bf16x8 bg[4];   // 4 N frags

#pragma unroll 1
  for (int t = 0; t < NK3; ++t) {
    const int d = t & 1;
    const int k2 = (t + 2) * BK3;
    const bool stg = (t + 2) < NK3;
    const unsigned short* hA = lsA + d * 4096 + wr * 2048;          // 64-row half
    const unsigned short* hB = lsB + d * 8192 + (wc >> 1) * 4096;   // 128-row half
    const int rB0 = (wc & 1) * 64;

    // ---------- ph0: gate tile t; read A(4) + B-n01(2); MFMA 4x2 ----
    if (t >= NK3 - 2) { WVM0; } else { WVM3; }
    BAR;
#pragma unroll
    for (int m = 0; m < 4; ++m) {
      const int lr = m * 16 + l15;                   // 0..63 within wave's half
      af[m] = *(const bf16x8*)&hA[lr * 32 + ((kq ^ ((lr >> 1) & 3)) * 8)];
    }
#pragma unroll
    for (int n = 0; n < 2; ++n) {
      const int lr = rB0 + n * 16 + l15;             // 0..127 within B half
      bg[n] = *(const bf16x8*)&hB[lr * 32 + ((kq ^ ((lr >> 1) & 3)) * 8)];
    }
    WLG0;
    __builtin_amdgcn_s_setprio(1);
#pragma unroll
    for (int m = 0; m < 4; ++m)
#pragma unroll
      for (int n = 0; n < 2; ++n)
        acc[m][n] = __builtin_amdgcn_mfma_f32_16x16x32_bf16(af[m], bg[n], acc[m][n], 0, 0, 0);
    __builtin_amdgcn_s_setprio(0);
    FENCE;

    // ---------- ph1: read B-n23; all reads done -> stage(t+2); MFMA 4x2 ----
#pragma unroll
    for (int n = 2; n < 4; ++n) {
      const int lr = rB0 + n * 16 + l15;
      bg[n] = *(const bf16x8*)&hB[lr * 32 + ((kq ^ ((lr >> 1) & 3)) * 8)];
    }
    WLG0;
    BAR;                       // every wave's A+B reads complete -> dbuf d reusable
    if (stg) {
      SB32(lsB + d * 8192, k2)
      SA32(lsA + d * 4096, k2)
    }
    FENCE;
    __builtin_amdgcn_s_setprio(1);
#pragma unroll
    for (int m = 0; m < 4; ++m)
#pragma unroll
      for (int n = 2; n < 4; ++n)
        acc[m][n] = __builtin_amdgcn_mfma_f32_16x16x32_bf16(af[m], bg[n], acc[m][n], 0, 0, 0);
    __builtin_amdgcn_s_setprio(0);
    FENCE;
  }

  const int crow0 = bm * 128 + wr * 64;
  const int ccol0 = bn * 256 + wc * 64;
  const int rql = (lane >> 4) * 4;
  const int cl  = lane & 15;
#pragma unroll
  for (int n = 0; n < 4; ++n) {
    const int col = ccol0 + n * 16 + cl;
    if (col < NCLS) {
      const float bb = bias[col];
#pragma unroll
      for (int m = 0; m < 4; ++m) {
#pragma unroll
        for (int r = 0; r < 4; ++r) {
          const int row = crow0 + m * 16 + rql + r;
          C[(size_t)row * NCLS + col] = acc[m][n][r] + bb;
        }
      }
    }
  }
}

extern "C" void kernel_launch(void* const* d_in, const int* in_sizes, int n_in,
                              void* d_out, int out_size, void* d_ws, size_t ws_size,
                              hipStream_t stream) {
  const float* x    = (const float*)d_in[0];
  const float* p0   = (const float*)d_in[1];
  const float* W    = (const float*)d_in[2];
  const float* bias = (const float*)d_in[3];
  float* out = (float*)d_out;

  unsigned short* Wb    = (unsigned short*)d_ws;
  unsigned short* rateb = (unsigned short*)d_ws + WB_ELEMS;

  sim_kernel<<<dim3(NB / 4), dim3(256), 0, stream>>>(x, p0, W, Wb, rateb);
  gemm_kernel<<<dim3((NB / 128) * (NPAD / 256)), dim3(512), 0, stream>>>(rateb, Wb, bias, out);
}

// Round 21
// 293.420 us; speedup vs baseline: 1.0297x; 1.0297x over previous
//
#include <hip/hip_runtime.h>

#define NB 65536
#define NTOT 704
#define NCLS 1000
#define NPAD 1024
#define KDIM 704

typedef __attribute__((ext_vector_type(8))) short bf16x8;
typedef __attribute__((ext_vector_type(4))) float f32x4;
typedef __attribute__((ext_vector_type(2))) float f32x2;

#define WB_ELEMS (NPAD * KDIM)

__device__ __forceinline__ f32x2 sp(float x) { return (f32x2){x, x}; }

template <int CTRL>
__device__ __forceinline__ float dpp_shuf(float v) {
  return __int_as_float(__builtin_amdgcn_update_dpp(0, __float_as_int(v), CTRL, 0xF, 0xF, true));
}
__device__ __forceinline__ float swz16(float v) {
  return __int_as_float(__builtin_amdgcn_ds_swizzle(__float_as_int(v), 0x401F)); // xor 16
}
// all-lanes butterfly sum: xor1, xor2, half-mirror, mirror, xor16, xor32
__device__ __forceinline__ float wsum_f(float v) {
  v += dpp_shuf<0xB1>(v);   // quad_perm [1,0,3,2]
  v += dpp_shuf<0x4E>(v);   // quad_perm [2,3,0,1]
  v += dpp_shuf<0x141>(v);  // row_half_mirror
  v += dpp_shuf<0x140>(v);  // row_mirror
  v += swz16(v);
  v += __shfl_xor(v, 32, 64);
  return v;
}
__device__ __forceinline__ float wmax_f(float v) {
  v = fmaxf(v, dpp_shuf<0xB1>(v));
  v = fmaxf(v, dpp_shuf<0x4E>(v));
  v = fmaxf(v, dpp_shuf<0x141>(v));
  v = fmaxf(v, dpp_shuf<0x140>(v));
  v = fmaxf(v, swz16(v));
  v = fmaxf(v, __shfl_xor(v, 32, 64));
  return v;
}
__device__ __forceinline__ float wmin_f(float v) {
  v = fminf(v, dpp_shuf<0xB1>(v));
  v = fminf(v, dpp_shuf<0x4E>(v));
  v = fminf(v, dpp_shuf<0x141>(v));
  v = fminf(v, dpp_shuf<0x140>(v));
  v = fminf(v, swz16(v));
  v = fminf(v, __shfl_xor(v, 32, 64));
  return v;
}

__device__ __forceinline__ unsigned short f2bf(float v) {
  unsigned u = __float_as_uint(v);
  u = (u + 0x7FFFu + ((u >> 16) & 1u)) >> 16;   // RNE
  return (unsigned short)u;
}

__device__ __forceinline__ float freq_of(int i) {
  if (i < 64)       return 1.0f + 3.0f * (float)i * (1.0f / 63.0f);
  else if (i < 192) return 4.0f + 4.0f * (float)(i - 64) * (1.0f / 127.0f);
  else              return 30.0f + 50.0f * (float)(i - 192) * (1.0f / 511.0f);
}

// ---------------- oscillator sim + quantile gate -> rate(bf16) ----------------
// convw fused: first NPAD*KDIM/256 blocks also convert one W element to bf16.
__global__ __launch_bounds__(256) void sim_kernel(const float* __restrict__ x,
                                                  const float* __restrict__ p0,
                                                  const float* __restrict__ W,
                                                  unsigned short* __restrict__ Wb,
                                                  unsigned short* __restrict__ rateb) {
  // fused convw prologue (independent output; gemm launches after sim)
  {
    const int gid = blockIdx.x * 256 + threadIdx.x;
    if (gid < NPAD * KDIM) {
      const int n = gid / KDIM;
      Wb[gid] = f2bf((n < NCLS) ? W[gid] : 0.0f);
    }
  }

  const int wave = threadIdx.x >> 6;
  const int lane = threadIdx.x & 63;
  const int sample = blockIdx.x * 4 + wave;
  const size_t base = (size_t)sample * NTOT;

  // delta: scalar element (e=0); theta pair (1,2); gamma pairs (3,4)..(9,10)
  float sD, cD, ampD, dcD, dsD;
  f32x2 sPp[5], cPp[5], dc2[5], ds2[5], amp2[5];
  {
    const float p = p0[base + lane];
    sD = __builtin_amdgcn_sinf(p);
    cD = __builtin_amdgcn_cosf(p);
    ampD = fmaf(fabsf(x[base + lane]), 0.01f, 1.0f);
    const float rev = 0.01f * freq_of(lane);
    dcD = __builtin_amdgcn_cosf(rev);
    dsD = __builtin_amdgcn_sinf(rev);
  }
#pragma unroll
  for (int pr = 0; pr < 5; ++pr) {
    const int i0 = (1 + 2 * pr) * 64 + lane;
    const int i1 = i0 + 64;
    const float pa = p0[base + i0], pb = p0[base + i1];
    sPp[pr] = (f32x2){__builtin_amdgcn_sinf(pa), __builtin_amdgcn_sinf(pb)};
    cPp[pr] = (f32x2){__builtin_amdgcn_cosf(pa), __builtin_amdgcn_cosf(pb)};
    amp2[pr] = (f32x2){fmaf(fabsf(x[base + i0]), 0.01f, 1.0f),
                       fmaf(fabsf(x[base + i1]), 0.01f, 1.0f)};
    const float r0 = 0.01f * freq_of(i0);
    const float r1 = 0.01f * freq_of(i1);
    dc2[pr] = (f32x2){__builtin_amdgcn_cosf(r0), __builtin_amdgcn_cosf(r1)};
    ds2[pr] = (f32x2){__builtin_amdgcn_sinf(r0), __builtin_amdgcn_sinf(r1)};
  }

  float prodT = 1.0f, prodG = 1.0f;

#pragma unroll
  for (int st = 0; st < 5; ++st) {
    const float Sd = wsum_f(sD);
    const float Cd = wsum_f(cD);
    const float St = wsum_f(sPp[0].x + sPp[0].y);
    const float Ct = wsum_f(cPp[0].x + cPp[0].y);
    const f32x2 gs = (sPp[1] + sPp[2]) + (sPp[3] + sPp[4]);
    const f32x2 gc = (cPp[1] + cPp[2]) + (cPp[3] + cPp[4]);
    const float Sg = wsum_f(gs.x + gs.y);
    const float Cg = wsum_f(gc.x + gc.y);
    const float cpd = Cd * __builtin_amdgcn_rsqf(fmaf(Sd, Sd, Cd * Cd));
    const float cpt = Ct * __builtin_amdgcn_rsqf(fmaf(St, St, Ct * Ct));
    prodT *= fmaf(0.003f, cpd, 1.0f);
    prodG *= fmaf(0.003f, cpt, 1.0f);
    const float sdm = Sd * (0.02f / 64.0f),  cdm = Cd * (0.02f / 64.0f);
    const float stm = St * (0.02f / 128.0f), ctm = Ct * (0.02f / 128.0f);
    const float sgm = Sg * (0.02f / 512.0f), cgm = Cg * (0.02f / 512.0f);
    // delta (scalar), 1st-order rotor: cos(eps)~1, sin(eps)~eps (err eps^2/2 <= 2e-4)
    {
      const float eps = fmaf(-cdm, sD, sdm * cD);
      const float cd_ = fmaf(-dsD, eps, dcD);
      const float sd_ = fmaf(dcD, eps, dsD);
      const float sn = fmaf(cD, sd_, sD * cd_);
      const float cn = fmaf(-sD, sd_, cD * cd_);
      sD = sn; cD = cn;
    }
    // pairs (packed f32), 1st-order rotor
#pragma unroll
    for (int pr = 0; pr < 5; ++pr) {
      const f32x2 Sm = sp(pr == 0 ? stm : sgm);
      const f32x2 Cm = sp(pr == 0 ? ctm : cgm);
      const f32x2 s2 = sPp[pr], c2 = cPp[pr];
      const f32x2 eps = Sm * c2 - Cm * s2;
      const f32x2 cosd = dc2[pr] - ds2[pr] * eps;
      const f32x2 sind = ds2[pr] + dc2[pr] * eps;
      sPp[pr] = s2 * cosd + c2 * sind;
      cPp[pr] = c2 * cosd - s2 * sind;
    }
  }

  // rates + 14-bit keys
  float raw[11];
  unsigned kk[11];
  {
    const float h = 0.5f * ampD;
    raw[0] = fmaf(h, cD, h);
  }
  const float hT = 0.5f * prodT, hG = 0.5f * prodG;
#pragma unroll
  for (int pr = 0; pr < 5; ++pr) {
    const f32x2 h2 = amp2[pr] * sp(pr == 0 ? hT : hG);
    const f32x2 r2 = h2 * cPp[pr] + h2;
    raw[1 + 2 * pr] = r2.x;
    raw[2 + 2 * pr] = r2.y;
  }
#pragma unroll
  for (int e = 0; e < 11; ++e) kk[e] = (unsigned)(raw[e] * 8192.0f);

  // minimal B with count(k <= B) >= 633 — ballot+popcount (SALU-heavy)
  unsigned pre = 0;
#pragma unroll
  for (int bit = 13; bit >= 0; --bit) {
    const unsigned u = pre | ((1u << bit) - 1u);
    int cnt = 0;
#pragma unroll
    for (int e = 0; e < 11; ++e) cnt += (int)__popcll(__ballot(kk[e] <= u));
    if (cnt < 633) pre |= (1u << bit);
  }

  int clt = 0, ceq = 0;
#pragma unroll
  for (int e = 0; e < 11; ++e) {
    clt += (int)__popcll(__ballot(kk[e] < pre));
    ceq += (int)__popcll(__ballot(kk[e] == pre));
  }

  const float qv = 0.9f * 703.0f;
  float thr;
  if (clt + ceq >= 634) {
    // both order stats inside bucket (width 1/8192): center approx, err <= 1.2e-4
    thr = ((float)pre + 0.5f) * (1.0f / 8192.0f);
  } else {
    // exactly 633 values <= B: S632 = max(k==B), S633 = min(k>B)
    float mx = -1.0f, mn = 3.0e38f;
#pragma unroll
    for (int e = 0; e < 11; ++e) {
      mx = fmaxf(mx, (kk[e] == pre) ? raw[e] : -1.0f);
      mn = fminf(mn, (kk[e] > pre) ? raw[e] : 3.0e38f);
    }
    const float S632 = wmax_f(mx);
    const float S633 = wmin_f(mn);
    thr = S632 * (633.0f - qv) + S633 * (qv - 632.0f);
  }

#pragma unroll
  for (int e = 0; e < 11; ++e) {
    const float r = raw[e];
    const float t = __expf((thr - r) * 10.0f);
    const float sg = __builtin_amdgcn_rcpf(1.0f + t);
    rateb[base + e * 64 + lane] = f2bf(r * sg);
  }
}

// ---------------- bf16 MFMA GEMM: out = rate @ W^T + b ----------------
// R9/R16 (best measured total: 294.4 us): 256x256, BK=64, 8 waves (2Mx4N),
// 2 dbuf x 2 half per op (128 KB LDS). Counted-vmcnt, prefetch distance 2:
// tile t+2 staged into the CURRENTLY-READ dbuf after reads are
// lgkm-confirmed+barriered (B at ph1, A at ph2). vmcnt(8) gate at ph0.
// No "memory" clobbers: raw s_barrier + bare asm waitcnt + sched_barrier(0).
#define BK3 64
#define NK3 (KDIM / BK3)   // 11

#define FENCE __builtin_amdgcn_sched_barrier(0)
#define BAR   do { FENCE; __builtin_amdgcn_s_barrier(); FENCE; } while (0)
#define WVM8  do { asm volatile("s_waitcnt vmcnt(8)"); FENCE; } while (0)
#define WVM0  do { asm volatile("s_waitcnt vmcnt(0)"); FENCE; } while (0)
#define WLG0  do { asm volatile("s_waitcnt lgkmcnt(0)"); FENCE; } while (0)

__device__ __forceinline__ void gload16(const unsigned short* g, unsigned short* l) {
  __builtin_amdgcn_global_load_lds((const __attribute__((address_space(1))) void*)g,
                                   (__attribute__((address_space(3))) void*)l,
                                   16, 0, 0);
}

__global__ __launch_bounds__(512, 2) void gemm_kernel(const unsigned short* __restrict__ A,
                                                      const unsigned short* __restrict__ Bw,
                                                      const float* __restrict__ bias,
                                                      float* __restrict__ C) {
  // [dbuf][half][128 rows x 64 k] per operand = 4 x 16KB each
  __shared__ __align__(16) unsigned short lsA[4 * 8192];
  __shared__ __align__(16) unsigned short lsB[4 * 8192];
  const int tid  = threadIdx.x;
  const int wave = tid >> 6;
  const int lane = tid & 63;

  // XCD-bijective swizzle: nwg = 1024 = 8 * 128
  const int bid = blockIdx.x;
  const int swz = (bid & 7) * 128 + (bid >> 3);
  const int bm = swz >> 2;     // 0..255
  const int bn = swz & 3;      // 0..3

  const int wr = wave >> 2;    // 0..1  (M half -> A half)
  const int wc = wave & 3;     // 0..3  (N quarter -> B half wc>>1)

  f32x4 acc[8][4];
#pragma unroll
  for (int i = 0; i < 8; ++i)
#pragma unroll
    for (int j = 0; j < 4; ++j) acc[i][j] = (f32x4){0.f, 0.f, 0.f, 0.f};

  // staging: thread covers rows (tid>>3, +64) of a 128-row half, 16B col (tid&7)
  // pre-swizzled source col so LDS linear dest holds col^(row&7)-swizzled data
  const int srow = tid >> 3;                       // 0..63
  const int sc16 = ((tid & 7) ^ (srow & 7)) * 8;   // element offset in row
  const unsigned short* Ab = A  + (size_t)(bm * 256) * KDIM;
  const unsigned short* Bb = Bw + (size_t)(bn * 256) * KDIM;

#define SHALF(dst, srcb, rb, k0)                                                      \
  gload16((srcb) + (size_t)((rb) + srow) * KDIM + (k0) + sc16, (dst) + tid * 8);      \
  gload16((srcb) + (size_t)((rb) + 64 + srow) * KDIM + (k0) + sc16, (dst) + 4096 + tid * 8);

  // prologue: tiles 0 -> dbuf0, 1 -> dbuf1 (16 loads/thread)
  SHALF(lsA + 0 * 8192, Ab, 0, 0)
  SHALF(lsA + 1 * 8192, Ab, 128, 0)
  SHALF(lsB + 0 * 8192, Bb, 0, 0)
  SHALF(lsB + 1 * 8192, Bb, 128, 0)
  SHALF(lsA + 2 * 8192, Ab, 0, BK3)
  SHALF(lsA + 3 * 8192, Ab, 128, BK3)
  SHALF(lsB + 2 * 8192, Bb, 0, BK3)
  SHALF(lsB + 3 * 8192, Bb, 128, BK3)

  const int l15 = lane & 15;
  const int kq  = lane >> 4;   // 0..3

  bf16x8 af[4][2];   // current M-half quad of A frags (overwritten at ph2)
  bf16x8 bg[4][2];   // all 4 N frags of B

#pragma unroll 1
  for (int t = 0; t < NK3; ++t) {
    const int d = t & 1;
    const int k2 = (t + 2) * BK3;
    const bool stg = (t + 2) < NK3;
    const unsigned short* hA = lsA + (d * 2 + wr) * 8192;
    const unsigned short* hB = lsB + (d * 2 + (wc >> 1)) * 8192;
    const int rB0 = (wc & 1) * 64;

    // ---------- ph0: gate on tile t; read A-mh0 + B-n01; MFMA mh0 x n01 ----
    if (t == NK3 - 1) { WVM0; } else { WVM8; }
    BAR;
#pragma unroll
    for (int m = 0; m < 4; ++m) {
      const int lr = m * 16 + l15;
      af[m][0] = *(const bf16x8*)&hA[lr * 64 + ((kq ^ (lr & 7)) * 8)];
      af[m][1] = *(const bf16x8*)&hA[lr * 64 + (((kq + 4) ^ (lr & 7)) * 8)];
    }
#pragma unroll
    for (int n = 0; n < 2; ++n) {
      const int lr = rB0 + n * 16 + l15;
      bg[n][0] = *(const bf16x8*)&hB[lr * 64 + ((kq ^ (lr & 7)) * 8)];
      bg[n][1] = *(const bf16x8*)&hB[lr * 64 + (((kq + 4) ^ (lr & 7)) * 8)];
    }
    WLG0;
    __builtin_amdgcn_s_setprio(1);
#pragma unroll
    for (int m = 0; m < 4; ++m)
#pragma unroll
      for (int n = 0; n < 2; ++n) {
        acc[m][n] = __builtin_amdgcn_mfma_f32_16x16x32_bf16(af[m][0], bg[n][0], acc[m][n], 0, 0, 0);
        acc[m][n] = __builtin_amdgcn_mfma_f32_16x16x32_bf16(af[m][1], bg[n][1], acc[m][n], 0, 0, 0);
      }
    __builtin_amdgcn_s_setprio(0);
    FENCE;

    // ---------- ph1: read B-n23; (all B reads done) -> stage B(t+2); MFMA mh0 x n23 ----
#pragma unroll
    for (int n = 2; n < 4; ++n) {
      const int lr = rB0 + n * 16 + l15;
      bg[n][0] = *(const bf16x8*)&hB[lr * 64 + ((kq ^ (lr & 7)) * 8)];
      bg[n][1] = *(const bf16x8*)&hB[lr * 64 + (((kq + 4) ^ (lr & 7)) * 8)];
    }
    WLG0;
    BAR;                       // every wave's B reads complete -> B dbuf d reusable
    if (stg) {
      SHALF(lsB + (d * 2 + 0) * 8192, Bb, 0, k2)
      SHALF(lsB + (d * 2 + 1) * 8192, Bb, 128, k2)
    }
    FENCE;
    __builtin_amdgcn_s_setprio(1);
#pragma unroll
    for (int m = 0; m < 4; ++m)
#pragma unroll
      for (int n = 2; n < 4; ++n) {
        acc[m][n] = __builtin_amdgcn_mfma_f32_16x16x32_bf16(af[m][0], bg[n][0], acc[m][n], 0, 0, 0);
        acc[m][n] = __builtin_amdgcn_mfma_f32_16x16x32_bf16(af[m][1], bg[n][1], acc[m][n], 0, 0, 0);
      }
    __builtin_amdgcn_s_setprio(0);
    FENCE;

    // ---------- ph2: read A-mh1; (all A reads done) -> stage A(t+2); MFMA mh1 x n01 ----
#pragma unroll
    for (int m = 0; m < 4; ++m) {
      const int lr = (m + 4) * 16 + l15;
      af[m][0] = *(const bf16x8*)&hA[lr * 64 + ((kq ^ (lr & 7)) * 8)];
      af[m][1] = *(const bf16x8*)&hA[lr * 64 + (((kq + 4) ^ (lr & 7)) * 8)];
    }
    WLG0;
    BAR;                       // every wave's A reads complete -> A dbuf d reusable
    if (stg) {
      SHALF(lsA + (d * 2 + 0) * 8192, Ab, 0, k2)
      SHALF(lsA + (d * 2 + 1) * 8192, Ab, 128, k2)
    }
    FENCE;
    __builtin_amdgcn_s_setprio(1);
#pragma unroll
    for (int m = 0; m < 4; ++m)
#pragma unroll
      for (int n = 0; n < 2; ++n) {
        acc[m + 4][n] = __builtin_amdgcn_mfma_f32_16x16x32_bf16(af[m][0], bg[n][0], acc[m + 4][n], 0, 0, 0);
        acc[m + 4][n] = __builtin_amdgcn_mfma_f32_16x16x32_bf16(af[m][1], bg[n][1], acc[m + 4][n], 0, 0, 0);
      }
    __builtin_amdgcn_s_setprio(0);
    FENCE;

    // ---------- ph3: MFMA mh1 x n23 (register-only) ----------
    __builtin_amdgcn_s_setprio(1);
#pragma unroll
    for (int m = 0; m < 4; ++m)
#pragma unroll
      for (int n = 2; n < 4; ++n) {
        acc[m + 4][n] = __builtin_amdgcn_mfma_f32_16x16x32_bf16(af[m][0], bg[n][0], acc[m + 4][n], 0, 0, 0);
        acc[m + 4][n] = __builtin_amdgcn_mfma_f32_16x16x32_bf16(af[m][1], bg[n][1], acc[m + 4][n], 0, 0, 0);
      }
    __builtin_amdgcn_s_setprio(0);
    FENCE;
  }

  const int crow0 = bm * 256 + wr * 128;
  const int ccol0 = bn * 256 + wc * 64;
  const int rql = (lane >> 4) * 4;
  const int cl  = lane & 15;
#pragma unroll
  for (int n = 0; n < 4; ++n) {
    const int col = ccol0 + n * 16 + cl;
    if (col < NCLS) {
      const float bb = bias[col];
#pragma unroll
      for (int m = 0; m < 8; ++m) {
#pragma unroll
        for (int r = 0; r < 4; ++r) {
          const int row = crow0 + m * 16 + rql + r;
          C[(size_t)row * NCLS + col] = acc[m][n][r] + bb;
        }
      }
    }
  }
}

extern "C" void kernel_launch(void* const* d_in, const int* in_sizes, int n_in,
                              void* d_out, int out_size, void* d_ws, size_t ws_size,
                              hipStream_t stream) {
  const float* x    = (const float*)d_in[0];
  const float* p0   = (const float*)d_in[1];
  const float* W    = (const float*)d_in[2];
  const float* bias = (const float*)d_in[3];
  float* out = (float*)d_out;

  unsigned short* Wb    = (unsigned short*)d_ws;
  unsigned short* rateb = (unsigned short*)d_ws + WB_ELEMS;

  sim_kernel<<<dim3(NB / 4), dim3(256), 0, stream>>>(x, p0, W, Wb, rateb);
  gemm_kernel<<<dim3((NB / 256) * (NPAD / 256)), dim3(512), 0, stream>>>(rateb, Wb, bias, out);
}